// Round 6
// baseline (58.318 us; speedup 1.0000x reference)
//
#include <hip/hip_runtime.h>

// LLR denoiser, three-phase, atomic-free, all-linear memory streams:
//   Phase 1 (llr_zs):   per patch p, S_p = alpha_p * Zhat_p (~ THS*G^{-1/2})
//                       via register-resident Newton-Schulz; bf16 to ws.
//   Phase 2 (llr_cellw): per 4x4 stride cell, W = (sum of covering S_p)/cnt,
//                       written to global (512B/cell, zs-like packed layout).
//   Phase 3 (llr_apply): out = x - W*x. W read as one contiguous 8KB/wave
//                       linear stream -> LDS; x prefetched; pure-VALU matvec.
// All kernels use the same XCD-bijective blockIdx swizzle so producer and
// consumer of each intermediate live on the same XCD's L2.

#define NBATCH  2
#define NCH     16
#define HDIM    512
#define WDIM    512
#define NPH     127
#define NPW     127
#define NPATCH  (NBATCH * NPH * NPW)
#define NCELL   128
#define THS     0.1f
#define NSIT    8

typedef short bf16x8 __attribute__((ext_vector_type(8)));
typedef float f32x4  __attribute__((ext_vector_type(4)));

#define MFMA(a,b,c) __builtin_amdgcn_mfma_f32_16x16x32_bf16((a),(b),(c),0,0,0)

static __device__ inline short f2bf(float x) {
  return __builtin_bit_cast(short, (__bf16)x);   // native RNE convert
}
static __device__ inline float blo2f(unsigned int v) {
  return __builtin_bit_cast(float, v << 16);
}
static __device__ inline float bhi2f(unsigned int v) {
  return __builtin_bit_cast(float, v & 0xffff0000u);
}
static __device__ inline unsigned int pack2bf(float lo, float hi) {
  unsigned int a = (unsigned short)f2bf(lo);
  unsigned int b = (unsigned short)f2bf(hi);
  return (b << 16) | a;
}

// bijective XCD swizzle (m204): HW places block b on XCD b%8; give XCD x a
// contiguous chunk of the work range.
static __device__ inline int xcd_swz(int b, int nwg) {
  const int q = nwg >> 3, r = nwg & 7;
  const int x = b & 7, lo = b >> 3;
  return (x < r ? x * (q + 1) : r * (q + 1) + (x - r) * q) + lo;
}

static __device__ inline bf16x8 fragc(f32x4 v) {
  // symmetric-matrix C-layout -> MFMA A/B fragment (16 nonzero k-slots)
  bf16x8 r;
  r[0] = f2bf(v[0]); r[1] = f2bf(v[1]); r[2] = f2bf(v[2]); r[3] = f2bf(v[3]);
  r[4] = 0; r[5] = 0; r[6] = 0; r[7] = 0;
  return r;
}

// ---------------- Phase 1: per-patch scaled inverse-sqrt matrices ----------
// 256 threads = 4 waves = 4 consecutive patches per block.
#define ZS_NBLK ((NPATCH + 3) / 4)
__global__ __launch_bounds__(256) void llr_zs(const float* __restrict__ x,
                                              uint2* __restrict__ zs) {
  const int blk = xcd_swz(blockIdx.x, ZS_NBLK);
  const int pid = blk * 4 + (threadIdx.x >> 6);  // one wave per patch
  if (pid >= NPATCH) return;
  const int bi  = pid / (NPH * NPW);
  const int pr  = pid % (NPH * NPW);
  const int ph  = pr / NPW, pw = pr % NPW;
  const int h0  = ph * 4, w0 = pw * 4;
  const int l   = threadIdx.x & 63;
  const int j   = l & 15;                      // row/col id in 16x16 tiles
  const int u   = l >> 4;                      // k-group 0..3

  const size_t HW = (size_t)HDIM * WDIM;
  const float* xb = x + (size_t)bi * NCH * HW;

  // load M (16 channels x 64 pixels) in A-frag layout
  const float* pb = xb + (size_t)j * HW + (size_t)h0 * WDIM + w0;
  const int dh0 = (u >> 1), dw0 = 4 * (u & 1);
  float4 q0 = *(const float4*)(pb + (size_t)(dh0 + 0) * WDIM + dw0);
  float4 q1 = *(const float4*)(pb + (size_t)(dh0 + 2) * WDIM + dw0);
  float4 q2 = *(const float4*)(pb + (size_t)(dh0 + 4) * WDIM + dw0);
  float4 q3 = *(const float4*)(pb + (size_t)(dh0 + 6) * WDIM + dw0);

  bf16x8 m0, m1;
  m0[0]=f2bf(q0.x); m0[1]=f2bf(q0.y); m0[2]=f2bf(q0.z); m0[3]=f2bf(q0.w);
  m0[4]=f2bf(q1.x); m0[5]=f2bf(q1.y); m0[6]=f2bf(q1.z); m0[7]=f2bf(q1.w);
  m1[0]=f2bf(q2.x); m1[1]=f2bf(q2.y); m1[2]=f2bf(q2.z); m1[3]=f2bf(q2.w);
  m1[4]=f2bf(q3.x); m1[5]=f2bf(q3.y); m1[6]=f2bf(q3.z); m1[7]=f2bf(q3.w);

  // G = M M^T
  f32x4 g = {0.f, 0.f, 0.f, 0.f};
  g = MFMA(m0, m0, g);
  g = MFMA(m1, m1, g);

  // Frobenius norm^2 of G
  float s2 = g[0]*g[0] + g[1]*g[1] + g[2]*g[2] + g[3]*g[3];
  #pragma unroll
  for (int m = 32; m >= 1; m >>= 1) s2 += __shfl_xor(s2, m, 64);

  uint2 wv = {0u, 0u};
  if (s2 > 1e-20f) {
    const float invf  = rsqrtf(s2);            // 1/f, f = ||G||_F >= lmax
    const float gsc   = 2.0f * invf;           // normalize by t = f/2 (eig in (0,2])
    const float alpha = THS * sqrtf(gsc);      // THS / sqrt(t)

    // coupled Newton-Schulz: Y0 = G/t, Z0 = I; Z -> (G/t)^{-1/2}
    f32x4 Yc, Zc;
    #pragma unroll
    for (int r = 0; r < 4; ++r) {
      Yc[r] = g[r] * gsc;
      Zc[r] = (4 * u + r == j) ? 1.0f : 0.0f;
    }

    const f32x4 zero = {0.f, 0.f, 0.f, 0.f};
    for (int it = 0; it < NSIT - 1; ++it) {
      bf16x8 yF = fragc(Yc), zF = fragc(Zc);
      f32x4 t  = MFMA(zF, yF, zero);           // T = Z*Y
      bf16x8 tF = fragc(t);
      f32x4 py = MFMA(yF, tF, zero);           // Y*T
      f32x4 pz = MFMA(tF, zF, zero);           // T*Z
      #pragma unroll
      for (int r = 0; r < 4; ++r) {
        Yc[r] = 1.5f * Yc[r] - 0.5f * py[r];
        Zc[r] = 1.5f * Zc[r] - 0.5f * pz[r];
      }
    }
    { // final iteration: only Z needed
      bf16x8 yF = fragc(Yc), zF = fragc(Zc);
      f32x4 t  = MFMA(zF, yF, zero);
      bf16x8 tF = fragc(t);
      f32x4 pz = MFMA(tF, zF, zero);
      #pragma unroll
      for (int r = 0; r < 4; ++r) Zc[r] = 1.5f * Zc[r] - 0.5f * pz[r];
    }

    wv.x = pack2bf(alpha * Zc[0], alpha * Zc[1]);
    wv.y = pack2bf(alpha * Zc[2], alpha * Zc[3]);
  }
  zs[(size_t)pid * 64 + l] = wv;               // coalesced 512B per patch
}

// ---------------- Phase 2: per-cell summed W matrices to global ------------
// One wave per 16 cells; no other state held -> the 64 independent zs loads
// (L2-hot, same XCD as producer) pipeline freely. 512B/cell, lane t holds
// rows 4u..4u+3 (u=t>>4) col j=t&15 as two packed-bf16 dwords at dword 2t.
#define CW_NBLK (NBATCH * NCELL * (NCELL / 16))   // 2048
__global__ __launch_bounds__(64) void llr_cellw(const uint2* __restrict__ zs,
                                                uint2* __restrict__ cwg) {
  const int bid = xcd_swz(blockIdx.x, CW_NBLK);  // bi*1024 + ci*8 + wq
  const int wq  = bid & 7;
  const int ci  = (bid >> 3) & 127;
  const int bi  = bid >> 10;
  const int t   = threadIdx.x;

  const float cnth = 2.0f - (ci == 0) - (ci == NPH);
  #pragma unroll
  for (int i = 0; i < 16; ++i) {
    const int cj = wq * 16 + i;                // global cell col 0..127
    float a0 = 0.f, a1 = 0.f, a2 = 0.f, a3 = 0.f;
    #pragma unroll
    for (int a = 0; a < 2; ++a) {
      const int ph = ci - 1 + a;
      if ((unsigned)ph > (unsigned)(NPH - 1)) continue;
      #pragma unroll
      for (int b = 0; b < 2; ++b) {
        const int pw = cj - 1 + b;
        if ((unsigned)pw > (unsigned)(NPW - 1)) continue;
        uint2 z = zs[((size_t)((bi * NPH + ph) * NPW + pw)) * 64 + t];
        a0 += blo2f(z.x); a1 += bhi2f(z.x);
        a2 += blo2f(z.y); a3 += bhi2f(z.y);
      }
    }
    const float cntw = 2.0f - (cj == 0) - (cj == NPW);
    const float s = 1.0f / (cnth * cntw);
    const size_t cell = (size_t)(bi * NCELL + ci) * NCELL + cj;
    uint2 o;
    o.x = pack2bf(s * a0, s * a1);             // rows (4u, 4u+1), col j
    o.y = pack2bf(s * a2, s * a3);             // rows (4u+2, 4u+3), col j
    cwg[cell * 64 + t] = o;                    // coalesced 512B per cell
  }
}

// ---------------- Phase 3: apply out = x - W*x -----------------------------
// One wave per 16 cells (one cell-row strip). x prefetched (16 dwordx4);
// W = one contiguous 8KB linear stream -> LDS (b128 writes, padded rows).
// Dword layout per cell block (128 dwords): d = 32u + 2j + w holds packed
// rows (4u+2w, 4u+2w+1), col j  ==  rp = 2u+w: d = 32*(rp>>1) + 2j + (rp&1).
#define AP_NBLK (NBATCH * NCELL * (NCELL / 16))   // 2048
__global__ __launch_bounds__(64) void llr_apply(const float* __restrict__ x,
                                                const uint2* __restrict__ cwg,
                                                float* __restrict__ out) {
  __shared__ unsigned int P2[16 * 132];        // 132-dword pitch: b128-aligned,
                                               // stage-2 reads 2-way (free)
  const int bid = xcd_swz(blockIdx.x, AP_NBLK); // bi*1024 + ci*8 + wq
  const int wq  = bid & 7;
  const int ci  = (bid >> 3) & 127;
  const int bi  = bid >> 10;
  const int t   = threadIdx.x;

  const size_t HW = (size_t)HDIM * WDIM;
  const float* xb = x + (size_t)bi * NCH * HW;
  float* ob = out + (size_t)bi * NCH * HW;

  // ---- prefetch x: 16 coalesced dwordx4 (longest latency, issue first)
  const int r  = t >> 4;                       // 0..3 (h row in cell-row)
  const int cw = t & 15;                       // 0..15 (cell in block)
  const int h  = 4 * ci + r;
  const int w0 = wq * 64 + 4 * cw;
  const float* px = xb + (size_t)h * WDIM + w0;
  float4 xv[16];
  #pragma unroll
  for (int e = 0; e < 16; ++e) xv[e] = *(const float4*)(px + e * HW);

  // ---- W: 16 cells x 512B contiguous; linear load -> LDS
  const size_t cell0 = (size_t)(bi * NCELL + ci) * NCELL + wq * 16;
  const uint4* wg = (const uint4*)(cwg + cell0 * 64);  // 512 uint4 total
  #pragma unroll
  for (int k = 0; k < 8; ++k) {
    uint4 v = wg[k * 64 + t];
    const int gl = k * 256 + 4 * t;            // global dword index
    const int cl = gl >> 7;                    // cell_local 0..15
    const int id = gl & 127;                   // dword within cell (mult of 4)
    *(uint4*)&P2[cl * 132 + id] = v;           // 16B-aligned ds_write_b128
  }
  // single wave: no __syncthreads needed (lgkmcnt ordering by compiler)

  // ---- matvec: out = x - W*x (channel pairs per packed LDS word)
  float* po = ob + (size_t)h * WDIM + w0;
  #pragma unroll
  for (int cp = 0; cp < 8; ++cp) {
    float4 d0 = {0.f, 0.f, 0.f, 0.f};
    float4 d1 = {0.f, 0.f, 0.f, 0.f};
    #pragma unroll
    for (int e = 0; e < 16; ++e) {
      const unsigned int wp = P2[cw * 132 + 32 * (cp >> 1) + 2 * e + (cp & 1)];
      const float wlo = blo2f(wp), whi = bhi2f(wp);
      d0.x += wlo * xv[e].x; d0.y += wlo * xv[e].y;
      d0.z += wlo * xv[e].z; d0.w += wlo * xv[e].w;
      d1.x += whi * xv[e].x; d1.y += whi * xv[e].y;
      d1.z += whi * xv[e].z; d1.w += whi * xv[e].w;
    }
    const int c0 = 2 * cp, c1 = 2 * cp + 1;
    float4 o0, o1;
    o0.x = xv[c0].x - d0.x; o0.y = xv[c0].y - d0.y;
    o0.z = xv[c0].z - d0.z; o0.w = xv[c0].w - d0.w;
    o1.x = xv[c1].x - d1.x; o1.y = xv[c1].y - d1.y;
    o1.z = xv[c1].z - d1.z; o1.w = xv[c1].w - d1.w;
    *(float4*)(po + (size_t)c0 * HW) = o0;
    *(float4*)(po + (size_t)c1 * HW) = o1;
  }
}

extern "C" void kernel_launch(void* const* d_in, const int* in_sizes, int n_in,
                              void* d_out, int out_size, void* d_ws, size_t ws_size,
                              hipStream_t stream) {
  const float* x = (const float*)d_in[0];
  float* out = (float*)d_out;
  uint2* zs  = (uint2*)d_ws;                           // 32258*512B = 16.5 MB
  uint2* cwg = (uint2*)((char*)d_ws + (size_t)NPATCH * 512);  // 32768*512B = 16.8 MB

  llr_zs<<<dim3(ZS_NBLK), dim3(256), 0, stream>>>(x, zs);
  llr_cellw<<<dim3(CW_NBLK), dim3(64), 0, stream>>>(zs, cwg);
  llr_apply<<<dim3(AP_NBLK), dim3(64), 0, stream>>>(x, cwg, out);
}

// Round 8
// 49.417 us; speedup vs baseline: 1.1801x; 1.1801x over previous
//
#include <hip/hip_runtime.h>

// LLR denoiser, two-phase, atomic-free:
//   Phase 1 (llr_zs): per patch p, S_p = alpha_p * Zhat_p (16x16 ~ THS*G^{-1/2})
//            via register-resident Newton-Schulz; stored bf16 to ws (C-layout).
//   Phase 2 (llr_strip): one block per cell-row strip (4 rows x 512 px).
//            Sliding window: rowsum[pw] = zs[ci-1][pw]+zs[ci][pw] built once in
//            LDS (coalesced linear loads); then W[cj] = rowsum[cj-1]+rowsum[cj]
//            and out = x - W*x/cnt. All global streams linear; one barrier.
// Both kernels use an XCD-bijective blockIdx swizzle for L2 locality.

#define NBATCH  2
#define NCH     16
#define HDIM    512
#define WDIM    512
#define NPH     127
#define NPW     127
#define NPATCH  (NBATCH * NPH * NPW)
#define NCELL   128
#define THS     0.1f
#define NSIT    8

typedef short bf16x8 __attribute__((ext_vector_type(8)));
typedef float f32x4  __attribute__((ext_vector_type(4)));

#define MFMA(a,b,c) __builtin_amdgcn_mfma_f32_16x16x32_bf16((a),(b),(c),0,0,0)

static __device__ inline short f2bf(float x) {
  return __builtin_bit_cast(short, (__bf16)x);   // native RNE convert
}
static __device__ inline float blo2f(unsigned int v) {
  return __builtin_bit_cast(float, v << 16);
}
static __device__ inline float bhi2f(unsigned int v) {
  return __builtin_bit_cast(float, v & 0xffff0000u);
}
static __device__ inline unsigned int pack2bf(float lo, float hi) {
  unsigned int a = (unsigned short)f2bf(lo);
  unsigned int b = (unsigned short)f2bf(hi);
  return (b << 16) | a;
}

// bijective XCD swizzle (m204): HW places block b on XCD b%8; give XCD x a
// contiguous chunk of the work range.
static __device__ inline int xcd_swz(int b, int nwg) {
  const int q = nwg >> 3, r = nwg & 7;
  const int x = b & 7, lo = b >> 3;
  return (x < r ? x * (q + 1) : r * (q + 1) + (x - r) * q) + lo;
}

static __device__ inline bf16x8 fragc(f32x4 v) {
  // symmetric-matrix C-layout -> MFMA A/B fragment (16 nonzero k-slots)
  bf16x8 r;
  r[0] = f2bf(v[0]); r[1] = f2bf(v[1]); r[2] = f2bf(v[2]); r[3] = f2bf(v[3]);
  r[4] = 0; r[5] = 0; r[6] = 0; r[7] = 0;
  return r;
}

// ---------------- Phase 1: per-patch scaled inverse-sqrt matrices ----------
// 256 threads = 4 waves = 4 consecutive patches per block.
#define ZS_NBLK ((NPATCH + 3) / 4)
__global__ __launch_bounds__(256) void llr_zs(const float* __restrict__ x,
                                              uint2* __restrict__ zs) {
  const int blk = xcd_swz(blockIdx.x, ZS_NBLK);
  const int pid = blk * 4 + (threadIdx.x >> 6);  // one wave per patch
  if (pid >= NPATCH) return;
  const int bi  = pid / (NPH * NPW);
  const int pr  = pid % (NPH * NPW);
  const int ph  = pr / NPW, pw = pr % NPW;
  const int h0  = ph * 4, w0 = pw * 4;
  const int l   = threadIdx.x & 63;
  const int j   = l & 15;                      // row/col id in 16x16 tiles
  const int u   = l >> 4;                      // k-group 0..3

  const size_t HW = (size_t)HDIM * WDIM;
  const float* xb = x + (size_t)bi * NCH * HW;

  // load M (16 channels x 64 pixels) in A-frag layout
  const float* pb = xb + (size_t)j * HW + (size_t)h0 * WDIM + w0;
  const int dh0 = (u >> 1), dw0 = 4 * (u & 1);
  float4 q0 = *(const float4*)(pb + (size_t)(dh0 + 0) * WDIM + dw0);
  float4 q1 = *(const float4*)(pb + (size_t)(dh0 + 2) * WDIM + dw0);
  float4 q2 = *(const float4*)(pb + (size_t)(dh0 + 4) * WDIM + dw0);
  float4 q3 = *(const float4*)(pb + (size_t)(dh0 + 6) * WDIM + dw0);

  bf16x8 m0, m1;
  m0[0]=f2bf(q0.x); m0[1]=f2bf(q0.y); m0[2]=f2bf(q0.z); m0[3]=f2bf(q0.w);
  m0[4]=f2bf(q1.x); m0[5]=f2bf(q1.y); m0[6]=f2bf(q1.z); m0[7]=f2bf(q1.w);
  m1[0]=f2bf(q2.x); m1[1]=f2bf(q2.y); m1[2]=f2bf(q2.z); m1[3]=f2bf(q2.w);
  m1[4]=f2bf(q3.x); m1[5]=f2bf(q3.y); m1[6]=f2bf(q3.z); m1[7]=f2bf(q3.w);

  // G = M M^T
  f32x4 g = {0.f, 0.f, 0.f, 0.f};
  g = MFMA(m0, m0, g);
  g = MFMA(m1, m1, g);

  // Frobenius norm^2 of G
  float s2 = g[0]*g[0] + g[1]*g[1] + g[2]*g[2] + g[3]*g[3];
  #pragma unroll
  for (int m = 32; m >= 1; m >>= 1) s2 += __shfl_xor(s2, m, 64);

  uint2 wv = {0u, 0u};
  if (s2 > 1e-20f) {
    const float invf  = rsqrtf(s2);            // 1/f, f = ||G||_F >= lmax
    const float gsc   = 2.0f * invf;           // normalize by t = f/2 (eig in (0,2])
    const float alpha = THS * sqrtf(gsc);      // THS / sqrt(t)

    // coupled Newton-Schulz: Y0 = G/t, Z0 = I; Z -> (G/t)^{-1/2}
    f32x4 Yc, Zc;
    #pragma unroll
    for (int r = 0; r < 4; ++r) {
      Yc[r] = g[r] * gsc;
      Zc[r] = (4 * u + r == j) ? 1.0f : 0.0f;
    }

    const f32x4 zero = {0.f, 0.f, 0.f, 0.f};
    for (int it = 0; it < NSIT - 1; ++it) {
      bf16x8 yF = fragc(Yc), zF = fragc(Zc);
      f32x4 t  = MFMA(zF, yF, zero);           // T = Z*Y
      bf16x8 tF = fragc(t);
      f32x4 py = MFMA(yF, tF, zero);           // Y*T
      f32x4 pz = MFMA(tF, zF, zero);           // T*Z
      #pragma unroll
      for (int r = 0; r < 4; ++r) {
        Yc[r] = 1.5f * Yc[r] - 0.5f * py[r];
        Zc[r] = 1.5f * Zc[r] - 0.5f * pz[r];
      }
    }
    { // final iteration: only Z needed
      bf16x8 yF = fragc(Yc), zF = fragc(Zc);
      f32x4 t  = MFMA(zF, yF, zero);
      bf16x8 tF = fragc(t);
      f32x4 pz = MFMA(tF, zF, zero);
      #pragma unroll
      for (int r = 0; r < 4; ++r) Zc[r] = 1.5f * Zc[r] - 0.5f * pz[r];
    }

    wv.x = pack2bf(alpha * Zc[0], alpha * Zc[1]);
    wv.y = pack2bf(alpha * Zc[2], alpha * Zc[3]);
  }
  zs[(size_t)pid * 64 + l] = wv;               // coalesced 512B per patch
}

// ---------------- Phase 2: strip apply with LDS sliding-window -------------
// Block = (bi, ci): 4 pixel rows x 512 w. 512 threads = (r = t>>7, q = t&127);
// thread owns float4 at (h = 4ci+r, w = 4q), all 16 channels (xv[16]).
// LDS rowsum layout per pw (128 dwords): d2 = 16*cp + e holds packed bf16
// (rows 2cp, 2cp+1), col e. 16B-unit rotation: unit s = ((d2>>2)+pw)&31.
#define ST_NBLK (NBATCH * NCELL)   // 256
__global__ __launch_bounds__(512) void llr_strip(const float* __restrict__ x,
                                                 const uint2* __restrict__ zs,
                                                 float* __restrict__ out) {
  __shared__ unsigned int P[NPW * 128];        // 127*128*4 = 65024 B

  const int bid = xcd_swz(blockIdx.x, ST_NBLK);
  const int ci  = bid & (NCELL - 1);
  const int bi  = bid >> 7;
  const int t   = threadIdx.x;
  const int r   = t >> 7;                      // 0..3
  const int q   = t & 127;                     // 0..127 (cell column)

  const size_t HW = (size_t)HDIM * WDIM;
  const float* xb = x + (size_t)bi * NCH * HW;
  float* ob = out + (size_t)bi * NCH * HW;

  // ---- prefetch x: 16 fully-coalesced dwordx4 (1KB/wave-instr)
  const int h = 4 * ci + r;
  const float* px = xb + (size_t)h * WDIM + 4 * q;
  float4 xv[16];
  #pragma unroll
  for (int e = 0; e < 16; ++e) xv[e] = *(const float4*)(px + e * HW);

  // ---- phase A: rowsum[pw] = zs[ci-1][pw] + zs[ci][pw] -> LDS (bf16 packed)
  {
    const int w = t >> 6;                      // wave id 0..7
    const int l = t & 63;
    const int u = l >> 4, j = l & 15;
    const int ph0 = ci - 1, ph1 = ci;
    const bool v0 = (ph0 >= 0), v1 = (ph1 <= NPH - 1);
    const uint2* z0 = zs + (size_t)(bi * NPH + (v0 ? ph0 : 0)) * NPW * 64;
    const uint2* z1 = zs + (size_t)(bi * NPH + (v1 ? ph1 : 0)) * NPW * 64;
    const int d2x = 32 * u + j;                // cp = 2u  (rows 4u, 4u+1)
    const int d2y = 32 * u + 16 + j;           // cp = 2u+1 (rows 4u+2, 4u+3)
    #pragma unroll
    for (int i = 0; i < 16; ++i) {
      const int pw = 8 * i + w;                // wave-uniform
      if (pw >= NPW) continue;                 // pw == 127
      float s0 = 0.f, s1 = 0.f, s2 = 0.f, s3 = 0.f;
      if (v0) {
        uint2 a = z0[(size_t)pw * 64 + l];     // coalesced 512B
        s0 += blo2f(a.x); s1 += bhi2f(a.x); s2 += blo2f(a.y); s3 += bhi2f(a.y);
      }
      if (v1) {
        uint2 b = z1[(size_t)pw * 64 + l];
        s0 += blo2f(b.x); s1 += bhi2f(b.x); s2 += blo2f(b.y); s3 += bhi2f(b.y);
      }
      const int base = pw * 128;
      P[base + ((((d2x >> 2) + pw) & 31) << 2) + (d2x & 3)] = pack2bf(s0, s1);
      P[base + ((((d2y >> 2) + pw) & 31) << 2) + (d2y & 3)] = pack2bf(s2, s3);
    }
  }
  __syncthreads();

  // ---- phase B: out = x - (rowsum[q-1]+rowsum[q]) * x / cnt
  const int pwA = (q > 0) ? q - 1 : 0;         // boundary duplicates handled
  const int pwB = (q < 127) ? q : 126;         //   via dup=0.5 in the scale
  const float cnth = 2.0f - (ci == 0) - (ci == NCELL - 1);
  const float cntw = 2.0f - (q == 0) - (q == 127);
  const float dup  = (q == 0 || q == 127) ? 0.5f : 1.0f;
  const float s    = dup / (cnth * cntw);

  float* po = ob + (size_t)h * WDIM + 4 * q;
  #pragma unroll
  for (int cp = 0; cp < 8; ++cp) {
    float4 d0 = {0.f, 0.f, 0.f, 0.f};
    float4 d1 = {0.f, 0.f, 0.f, 0.f};
    #pragma unroll
    for (int k = 0; k < 4; ++k) {
      const int unit = 4 * cp + k;             // = d2>>2 for e = 4k..4k+3
      uint4 VA = *(const uint4*)&P[pwA * 128 + (((unit + pwA) & 31) << 2)];
      uint4 VB = *(const uint4*)&P[pwB * 128 + (((unit + pwB) & 31) << 2)];
      const unsigned int va[4] = {VA.x, VA.y, VA.z, VA.w};
      const unsigned int vb[4] = {VB.x, VB.y, VB.z, VB.w};
      #pragma unroll
      for (int c = 0; c < 4; ++c) {
        const int e = 4 * k + c;
        const float wlo = blo2f(va[c]) + blo2f(vb[c]);
        const float whi = bhi2f(va[c]) + bhi2f(vb[c]);
        d0.x += wlo * xv[e].x; d0.y += wlo * xv[e].y;
        d0.z += wlo * xv[e].z; d0.w += wlo * xv[e].w;
        d1.x += whi * xv[e].x; d1.y += whi * xv[e].y;
        d1.z += whi * xv[e].z; d1.w += whi * xv[e].w;
      }
    }
    const int c0 = 2 * cp, c1 = 2 * cp + 1;
    float4 o0, o1;
    o0.x = xv[c0].x - s * d0.x; o0.y = xv[c0].y - s * d0.y;
    o0.z = xv[c0].z - s * d0.z; o0.w = xv[c0].w - s * d0.w;
    o1.x = xv[c1].x - s * d1.x; o1.y = xv[c1].y - s * d1.y;
    o1.z = xv[c1].z - s * d1.z; o1.w = xv[c1].w - s * d1.w;
    *(float4*)(po + (size_t)c0 * HW) = o0;
    *(float4*)(po + (size_t)c1 * HW) = o1;
  }
}

extern "C" void kernel_launch(void* const* d_in, const int* in_sizes, int n_in,
                              void* d_out, int out_size, void* d_ws, size_t ws_size,
                              hipStream_t stream) {
  const float* x = (const float*)d_in[0];
  float* out = (float*)d_out;
  uint2* zs = (uint2*)d_ws;                    // 32258*512B = 16.5 MB

  llr_zs<<<dim3(ZS_NBLK), dim3(256), 0, stream>>>(x, zs);
  llr_strip<<<dim3(ST_NBLK), dim3(512), 0, stream>>>(x, zs, out);
}

// Round 9
// 48.803 us; speedup vs baseline: 1.1950x; 1.0126x over previous
//
#include <hip/hip_runtime.h>

// LLR denoiser, two-phase, atomic-free:
//   Phase 1 (llr_zs): per patch p, S_p = alpha_p * Zhat_p (16x16 ~ THS*G^{-1/2})
//            via register-resident Newton-Schulz; stored bf16 to ws (C-layout).
//   Phase 2 (llr_strip): block = 4-row x 128-px segment (32 cells). Phase A
//            builds per-cell W = (sum of covering S_p)/cnt in LDS (16 KB,
//            rotated layout); phase B: out = x - W*x, thread = float2 x 16ch.
//            float2 tile keeps live state ~70 VGPR -> launch_bounds(256,4)
//            guarantees no scratch spill (R8 failure: VGPR=60 < xv alone).
// Both kernels use an XCD-bijective blockIdx swizzle for L2 locality.

#define NBATCH  2
#define NCH     16
#define HDIM    512
#define WDIM    512
#define NPH     127
#define NPW     127
#define NPATCH  (NBATCH * NPH * NPW)
#define NCELL   128
#define THS     0.1f
#define NSIT    8

typedef short bf16x8 __attribute__((ext_vector_type(8)));
typedef float f32x4  __attribute__((ext_vector_type(4)));

#define MFMA(a,b,c) __builtin_amdgcn_mfma_f32_16x16x32_bf16((a),(b),(c),0,0,0)

static __device__ inline short f2bf(float x) {
  return __builtin_bit_cast(short, (__bf16)x);   // native RNE convert
}
static __device__ inline float blo2f(unsigned int v) {
  return __builtin_bit_cast(float, v << 16);
}
static __device__ inline float bhi2f(unsigned int v) {
  return __builtin_bit_cast(float, v & 0xffff0000u);
}
static __device__ inline unsigned int pack2bf(float lo, float hi) {
  unsigned int a = (unsigned short)f2bf(lo);
  unsigned int b = (unsigned short)f2bf(hi);
  return (b << 16) | a;
}

// bijective XCD swizzle (m204): HW places block b on XCD b%8; give XCD x a
// contiguous chunk of the work range.
static __device__ inline int xcd_swz(int b, int nwg) {
  const int q = nwg >> 3, r = nwg & 7;
  const int x = b & 7, lo = b >> 3;
  return (x < r ? x * (q + 1) : r * (q + 1) + (x - r) * q) + lo;
}

static __device__ inline bf16x8 fragc(f32x4 v) {
  // symmetric-matrix C-layout -> MFMA A/B fragment (16 nonzero k-slots)
  bf16x8 r;
  r[0] = f2bf(v[0]); r[1] = f2bf(v[1]); r[2] = f2bf(v[2]); r[3] = f2bf(v[3]);
  r[4] = 0; r[5] = 0; r[6] = 0; r[7] = 0;
  return r;
}

// ---------------- Phase 1: per-patch scaled inverse-sqrt matrices ----------
// 256 threads = 4 waves = 4 consecutive patches per block.
#define ZS_NBLK ((NPATCH + 3) / 4)
__global__ __launch_bounds__(256) void llr_zs(const float* __restrict__ x,
                                              uint2* __restrict__ zs) {
  const int blk = xcd_swz(blockIdx.x, ZS_NBLK);
  const int pid = blk * 4 + (threadIdx.x >> 6);  // one wave per patch
  if (pid >= NPATCH) return;
  const int bi  = pid / (NPH * NPW);
  const int pr  = pid % (NPH * NPW);
  const int ph  = pr / NPW, pw = pr % NPW;
  const int h0  = ph * 4, w0 = pw * 4;
  const int l   = threadIdx.x & 63;
  const int j   = l & 15;                      // row/col id in 16x16 tiles
  const int u   = l >> 4;                      // k-group 0..3

  const size_t HW = (size_t)HDIM * WDIM;
  const float* xb = x + (size_t)bi * NCH * HW;

  // load M (16 channels x 64 pixels) in A-frag layout
  const float* pb = xb + (size_t)j * HW + (size_t)h0 * WDIM + w0;
  const int dh0 = (u >> 1), dw0 = 4 * (u & 1);
  float4 q0 = *(const float4*)(pb + (size_t)(dh0 + 0) * WDIM + dw0);
  float4 q1 = *(const float4*)(pb + (size_t)(dh0 + 2) * WDIM + dw0);
  float4 q2 = *(const float4*)(pb + (size_t)(dh0 + 4) * WDIM + dw0);
  float4 q3 = *(const float4*)(pb + (size_t)(dh0 + 6) * WDIM + dw0);

  bf16x8 m0, m1;
  m0[0]=f2bf(q0.x); m0[1]=f2bf(q0.y); m0[2]=f2bf(q0.z); m0[3]=f2bf(q0.w);
  m0[4]=f2bf(q1.x); m0[5]=f2bf(q1.y); m0[6]=f2bf(q1.z); m0[7]=f2bf(q1.w);
  m1[0]=f2bf(q2.x); m1[1]=f2bf(q2.y); m1[2]=f2bf(q2.z); m1[3]=f2bf(q2.w);
  m1[4]=f2bf(q3.x); m1[5]=f2bf(q3.y); m1[6]=f2bf(q3.z); m1[7]=f2bf(q3.w);

  // G = M M^T
  f32x4 g = {0.f, 0.f, 0.f, 0.f};
  g = MFMA(m0, m0, g);
  g = MFMA(m1, m1, g);

  // Frobenius norm^2 of G
  float s2 = g[0]*g[0] + g[1]*g[1] + g[2]*g[2] + g[3]*g[3];
  #pragma unroll
  for (int m = 32; m >= 1; m >>= 1) s2 += __shfl_xor(s2, m, 64);

  uint2 wv = {0u, 0u};
  if (s2 > 1e-20f) {
    const float invf  = rsqrtf(s2);            // 1/f, f = ||G||_F >= lmax
    const float gsc   = 2.0f * invf;           // normalize by t = f/2 (eig in (0,2])
    const float alpha = THS * sqrtf(gsc);      // THS / sqrt(t)

    // coupled Newton-Schulz: Y0 = G/t, Z0 = I; Z -> (G/t)^{-1/2}
    f32x4 Yc, Zc;
    #pragma unroll
    for (int r = 0; r < 4; ++r) {
      Yc[r] = g[r] * gsc;
      Zc[r] = (4 * u + r == j) ? 1.0f : 0.0f;
    }

    const f32x4 zero = {0.f, 0.f, 0.f, 0.f};
    for (int it = 0; it < NSIT - 1; ++it) {
      bf16x8 yF = fragc(Yc), zF = fragc(Zc);
      f32x4 t  = MFMA(zF, yF, zero);           // T = Z*Y
      bf16x8 tF = fragc(t);
      f32x4 py = MFMA(yF, tF, zero);           // Y*T
      f32x4 pz = MFMA(tF, zF, zero);           // T*Z
      #pragma unroll
      for (int r = 0; r < 4; ++r) {
        Yc[r] = 1.5f * Yc[r] - 0.5f * py[r];
        Zc[r] = 1.5f * Zc[r] - 0.5f * pz[r];
      }
    }
    { // final iteration: only Z needed
      bf16x8 yF = fragc(Yc), zF = fragc(Zc);
      f32x4 t  = MFMA(zF, yF, zero);
      bf16x8 tF = fragc(t);
      f32x4 pz = MFMA(tF, zF, zero);
      #pragma unroll
      for (int r = 0; r < 4; ++r) Zc[r] = 1.5f * Zc[r] - 0.5f * pz[r];
    }

    wv.x = pack2bf(alpha * Zc[0], alpha * Zc[1]);
    wv.y = pack2bf(alpha * Zc[2], alpha * Zc[3]);
  }
  zs[(size_t)pid * 64 + l] = wv;               // coalesced 512B per patch
}

// ---------------- Phase 2: segment apply -----------------------------------
// Block = (bi, ci, seg): 4 rows x 128 px = 32 cells. 256 threads:
//   wave r = t>>6 owns pixel row h = 4ci+r; lane q2 = t&63 owns float2 at
//   w = seg*128 + 2*q2; its cell is cl = q2>>1.
// Phase A: per-cell W (sum of <=4 covering S_p, scaled by 1/cnt) -> LDS.
//   W[c] = 128 dwords; pair p (out-ch 2p,2p+1), in-ch j at d2 = 16p + j,
//   stored rotated: dword = c*128 + (((d2>>2)+c)&31)*4 + (d2&3).
// Phase B: out = x - W*x; per (cp,k) ONE uint4 = in-ch 4k..4k+3 of pair cp.
#define ST_SEG  4
#define ST_NBLK (NBATCH * NCELL * ST_SEG)   // 1024 = 4 blocks/CU
__global__ __launch_bounds__(256, 4) void llr_strip(const float* __restrict__ x,
                                                    const uint2* __restrict__ zs,
                                                    float* __restrict__ out) {
  __shared__ unsigned int Wl[32 * 128];        // 16 KB

  const int bid = xcd_swz(blockIdx.x, ST_NBLK); // bi*512 + ci*4 + seg
  const int seg = bid & 3;
  const int ci  = (bid >> 2) & 127;
  const int bi  = bid >> 9;
  const int t   = threadIdx.x;
  const int r   = t >> 6;                      // wave id = pixel row 0..3
  const int q2  = t & 63;                      // f2-column in segment

  const size_t HW = (size_t)HDIM * WDIM;
  const float* xb = x + (size_t)bi * NCH * HW;
  float* ob = out + (size_t)bi * NCH * HW;

  // ---- prefetch x: 16 coalesced dwordx2 (issued before the gather)
  const int h   = 4 * ci + r;
  const int wpx = seg * 128 + 2 * q2;
  const float* px = xb + (size_t)h * WDIM + wpx;
  float2 xv[16];
  #pragma unroll
  for (int e = 0; e < 16; ++e) xv[e] = *(const float2*)(px + e * HW);

  // ---- phase A: per-cell W into LDS (each wave does 1 cell/round, 8 rounds)
  {
    const int l = t & 63;
    const int u = l >> 4, j = l & 15;
    const float cnth = 2.0f - (ci == 0) - (ci == NCELL - 1);
    const uint2* zb = zs + (size_t)bi * NPH * NPW * 64;
    #pragma unroll
    for (int rho = 0; rho < 8; ++rho) {
      const int c  = rho * 4 + r;              // cell 0..31 (wave-uniform)
      const int cj = seg * 32 + c;             // global cell col 0..127
      float a0 = 0.f, a1 = 0.f, a2 = 0.f, a3 = 0.f;
      #pragma unroll
      for (int dh = 0; dh < 2; ++dh) {
        const int ph = ci - 1 + dh;
        if ((unsigned)ph > (unsigned)(NPH - 1)) continue;
        #pragma unroll
        for (int dw = 0; dw < 2; ++dw) {
          const int pw = cj - 1 + dw;
          if ((unsigned)pw > (unsigned)(NPW - 1)) continue;
          uint2 z = zb[((size_t)ph * NPW + pw) * 64 + l];  // coalesced 512B
          a0 += blo2f(z.x); a1 += bhi2f(z.x);
          a2 += blo2f(z.y); a3 += bhi2f(z.y);
        }
      }
      const float cntw = 2.0f - (cj == 0) - (cj == NCELL - 1);
      const float s = 1.0f / (cnth * cntw);
      const int base = c * 128;
      const int u0 = 8 * u + (j >> 2);         // d2x>>2 (pair 2u)
      const int u1 = u0 + 4;                   // d2y>>2 (pair 2u+1)
      Wl[base + (((u0 + c) & 31) << 2) + (j & 3)] = pack2bf(s * a0, s * a1);
      Wl[base + (((u1 + c) & 31) << 2) + (j & 3)] = pack2bf(s * a2, s * a3);
    }
  }
  __syncthreads();

  // ---- phase B: out = x - W*x  (thread: one float2, all 16 channels)
  const int cl = q2 >> 1;                      // lane's cell 0..31
  float* po = ob + (size_t)h * WDIM + wpx;
  #pragma unroll
  for (int cp = 0; cp < 8; ++cp) {
    float2 d0 = {0.f, 0.f};
    float2 d1 = {0.f, 0.f};
    #pragma unroll
    for (int k = 0; k < 4; ++k) {
      const uint4 V = *(const uint4*)&Wl[cl * 128 + (((4 * cp + k + cl) & 31) << 2)];
      const unsigned int va[4] = {V.x, V.y, V.z, V.w};
      #pragma unroll
      for (int c = 0; c < 4; ++c) {
        const int e = 4 * k + c;
        const float wlo = blo2f(va[c]);        // out-ch 2cp,   in-ch e
        const float whi = bhi2f(va[c]);        // out-ch 2cp+1, in-ch e
        d0.x += wlo * xv[e].x; d0.y += wlo * xv[e].y;
        d1.x += whi * xv[e].x; d1.y += whi * xv[e].y;
      }
    }
    const int c0 = 2 * cp, c1 = 2 * cp + 1;
    float2 o0, o1;
    o0.x = xv[c0].x - d0.x; o0.y = xv[c0].y - d0.y;
    o1.x = xv[c1].x - d1.x; o1.y = xv[c1].y - d1.y;
    *(float2*)(po + (size_t)c0 * HW) = o0;
    *(float2*)(po + (size_t)c1 * HW) = o1;
  }
}

extern "C" void kernel_launch(void* const* d_in, const int* in_sizes, int n_in,
                              void* d_out, int out_size, void* d_ws, size_t ws_size,
                              hipStream_t stream) {
  const float* x = (const float*)d_in[0];
  float* out = (float*)d_out;
  uint2* zs = (uint2*)d_ws;                    // 32258*512B = 16.5 MB

  llr_zs<<<dim3(ZS_NBLK), dim3(256), 0, stream>>>(x, zs);
  llr_strip<<<dim3(ST_NBLK), dim3(256), 0, stream>>>(x, zs, out);
}

// Round 10
// 47.523 us; speedup vs baseline: 1.2271x; 1.0269x over previous
//
#include <hip/hip_runtime.h>

// LLR denoiser, two-phase, atomic-free:
//   Phase 1 (llr_zs): per patch p, S_p = alpha_p * Zhat_p (16x16 ~ THS*G^{-1/2})
//            via register-resident Newton-Schulz; stored bf16 to ws (C-layout).
//            XCD-swizzled (2D patch reuse -> L2 locality wins).
//   Phase 2 (llr_strip): block = 4-row x 128-px segment (32 cells); per-cell
//            W = (sum of covering S_p)/cnt in LDS; out = x - W*x.
//            NO XCD swizzle here: the 16 channel-planes sit 1MB apart (same
//            L2 channel); swizzled neighbors hammer identical channels in
//            lockstep (R3->R4: 27->41us). Round-robin + 4-way static channel
//            stagger decorrelates the streams.

#define NBATCH  2
#define NCH     16
#define HDIM    512
#define WDIM    512
#define NPH     127
#define NPW     127
#define NPATCH  (NBATCH * NPH * NPW)
#define NCELL   128
#define THS     0.1f
#define NSIT    8

typedef short bf16x8 __attribute__((ext_vector_type(8)));
typedef float f32x4  __attribute__((ext_vector_type(4)));

#define MFMA(a,b,c) __builtin_amdgcn_mfma_f32_16x16x32_bf16((a),(b),(c),0,0,0)

static __device__ inline short f2bf(float x) {
  return __builtin_bit_cast(short, (__bf16)x);   // native RNE convert
}
static __device__ inline float blo2f(unsigned int v) {
  return __builtin_bit_cast(float, v << 16);
}
static __device__ inline float bhi2f(unsigned int v) {
  return __builtin_bit_cast(float, v & 0xffff0000u);
}
static __device__ inline unsigned int pack2bf(float lo, float hi) {
  unsigned int a = (unsigned short)f2bf(lo);
  unsigned int b = (unsigned short)f2bf(hi);
  return (b << 16) | a;
}

// bijective XCD swizzle (m204) — used by llr_zs only
static __device__ inline int xcd_swz(int b, int nwg) {
  const int q = nwg >> 3, r = nwg & 7;
  const int x = b & 7, lo = b >> 3;
  return (x < r ? x * (q + 1) : r * (q + 1) + (x - r) * q) + lo;
}

static __device__ inline bf16x8 fragc(f32x4 v) {
  // symmetric-matrix C-layout -> MFMA A/B fragment (16 nonzero k-slots)
  bf16x8 r;
  r[0] = f2bf(v[0]); r[1] = f2bf(v[1]); r[2] = f2bf(v[2]); r[3] = f2bf(v[3]);
  r[4] = 0; r[5] = 0; r[6] = 0; r[7] = 0;
  return r;
}

// ---------------- Phase 1: per-patch scaled inverse-sqrt matrices ----------
// 256 threads = 4 waves = 4 consecutive patches per block.
#define ZS_NBLK ((NPATCH + 3) / 4)
__global__ __launch_bounds__(256) void llr_zs(const float* __restrict__ x,
                                              uint2* __restrict__ zs) {
  const int blk = xcd_swz(blockIdx.x, ZS_NBLK);
  const int pid = blk * 4 + (threadIdx.x >> 6);  // one wave per patch
  if (pid >= NPATCH) return;
  const int bi  = pid / (NPH * NPW);
  const int pr  = pid % (NPH * NPW);
  const int ph  = pr / NPW, pw = pr % NPW;
  const int h0  = ph * 4, w0 = pw * 4;
  const int l   = threadIdx.x & 63;
  const int j   = l & 15;                      // row/col id in 16x16 tiles
  const int u   = l >> 4;                      // k-group 0..3

  const size_t HW = (size_t)HDIM * WDIM;
  const float* xb = x + (size_t)bi * NCH * HW;

  // load M (16 channels x 64 pixels) in A-frag layout
  const float* pb = xb + (size_t)j * HW + (size_t)h0 * WDIM + w0;
  const int dh0 = (u >> 1), dw0 = 4 * (u & 1);
  float4 q0 = *(const float4*)(pb + (size_t)(dh0 + 0) * WDIM + dw0);
  float4 q1 = *(const float4*)(pb + (size_t)(dh0 + 2) * WDIM + dw0);
  float4 q2 = *(const float4*)(pb + (size_t)(dh0 + 4) * WDIM + dw0);
  float4 q3 = *(const float4*)(pb + (size_t)(dh0 + 6) * WDIM + dw0);

  bf16x8 m0, m1;
  m0[0]=f2bf(q0.x); m0[1]=f2bf(q0.y); m0[2]=f2bf(q0.z); m0[3]=f2bf(q0.w);
  m0[4]=f2bf(q1.x); m0[5]=f2bf(q1.y); m0[6]=f2bf(q1.z); m0[7]=f2bf(q1.w);
  m1[0]=f2bf(q2.x); m1[1]=f2bf(q2.y); m1[2]=f2bf(q2.z); m1[3]=f2bf(q2.w);
  m1[4]=f2bf(q3.x); m1[5]=f2bf(q3.y); m1[6]=f2bf(q3.z); m1[7]=f2bf(q3.w);

  // G = M M^T
  f32x4 g = {0.f, 0.f, 0.f, 0.f};
  g = MFMA(m0, m0, g);
  g = MFMA(m1, m1, g);

  // Frobenius norm^2 of G
  float s2 = g[0]*g[0] + g[1]*g[1] + g[2]*g[2] + g[3]*g[3];
  #pragma unroll
  for (int m = 32; m >= 1; m >>= 1) s2 += __shfl_xor(s2, m, 64);

  uint2 wv = {0u, 0u};
  if (s2 > 1e-20f) {
    const float invf  = rsqrtf(s2);            // 1/f, f = ||G||_F >= lmax
    const float gsc   = 2.0f * invf;           // normalize by t = f/2 (eig in (0,2])
    const float alpha = THS * sqrtf(gsc);      // THS / sqrt(t)

    // coupled Newton-Schulz: Y0 = G/t, Z0 = I; Z -> (G/t)^{-1/2}
    f32x4 Yc, Zc;
    #pragma unroll
    for (int r = 0; r < 4; ++r) {
      Yc[r] = g[r] * gsc;
      Zc[r] = (4 * u + r == j) ? 1.0f : 0.0f;
    }

    const f32x4 zero = {0.f, 0.f, 0.f, 0.f};
    for (int it = 0; it < NSIT - 1; ++it) {
      bf16x8 yF = fragc(Yc), zF = fragc(Zc);
      f32x4 t  = MFMA(zF, yF, zero);           // T = Z*Y
      bf16x8 tF = fragc(t);
      f32x4 py = MFMA(yF, tF, zero);           // Y*T
      f32x4 pz = MFMA(tF, zF, zero);           // T*Z
      #pragma unroll
      for (int r = 0; r < 4; ++r) {
        Yc[r] = 1.5f * Yc[r] - 0.5f * py[r];
        Zc[r] = 1.5f * Zc[r] - 0.5f * pz[r];
      }
    }
    { // final iteration: only Z needed
      bf16x8 yF = fragc(Yc), zF = fragc(Zc);
      f32x4 t  = MFMA(zF, yF, zero);
      bf16x8 tF = fragc(t);
      f32x4 pz = MFMA(tF, zF, zero);
      #pragma unroll
      for (int r = 0; r < 4; ++r) Zc[r] = 1.5f * Zc[r] - 0.5f * pz[r];
    }

    wv.x = pack2bf(alpha * Zc[0], alpha * Zc[1]);
    wv.y = pack2bf(alpha * Zc[2], alpha * Zc[3]);
  }
  zs[(size_t)pid * 64 + l] = wv;               // coalesced 512B per patch
}

// ---------------- Phase 2: segment apply -----------------------------------
// Block = (bi, ci, seg): 4 rows x 128 px = 32 cells. 256 threads:
//   wave r = t>>6 owns pixel row h = 4ci+r; lane q2 = t&63 owns float2 at
//   w = seg*128 + 2*q2; its cell is cl = q2>>1.
// Phase A (branch-free): per-cell W = sum of <=4 covering S_p (clamped
//   addresses, uniform post-load masking), batched 16 loads at a time.
// LDS: W[c] = 128 dwords; pair p, in-ch j at d2 = 16p+j, rotated by cell:
//   dword = c*128 + (((d2>>2)+c)&31)*4 + (d2&3).
#define ST_SEG  4
#define ST_NBLK (NBATCH * NCELL * ST_SEG)   // 1024 = 4 blocks/CU

#define XLOADS(OFF)                                              \
  _Pragma("unroll")                                              \
  for (int m = 0; m < 16; ++m) {                                 \
    const int e = (m + (OFF)) & 15;                              \
    xv[e] = *(const float2*)(px + (size_t)e * HW);               \
  }

__global__ __launch_bounds__(256, 4) void llr_strip(const float* __restrict__ x,
                                                    const uint2* __restrict__ zs,
                                                    float* __restrict__ out) {
  __shared__ unsigned int Wl[32 * 128];        // 16 KB

  const int bid = blockIdx.x;                  // NO swizzle (see header)
  const int seg = bid & 3;
  const int ci  = (bid >> 2) & 127;
  const int bi  = bid >> 9;
  const int t   = threadIdx.x;
  const int r   = t >> 6;                      // wave id = pixel row 0..3
  const int q2  = t & 63;                      // f2-column in segment

  const size_t HW = (size_t)HDIM * WDIM;
  const float* xb = x + (size_t)bi * NCH * HW;
  float* ob = out + (size_t)bi * NCH * HW;

  // ---- prefetch x: 16 coalesced dwordx2, 4-way channel-staggered
  const int h   = 4 * ci + r;
  const int wpx = seg * 128 + 2 * q2;
  const float* px = xb + (size_t)h * WDIM + wpx;
  float2 xv[16];
  switch ((bid + r) & 3) {                     // wave-uniform, static indexing
    case 0: XLOADS(0)  break;
    case 1: XLOADS(4)  break;
    case 2: XLOADS(8)  break;
    default: XLOADS(12) break;
  }

  // ---- phase A: per-cell W into LDS; loads clamped+unconditional, masked
  {
    const int l = t & 63;
    const int u = l >> 4, j = l & 15;
    const float cnth = 2.0f - (ci == 0) - (ci == NCELL - 1);
    const uint2* zb = zs + (size_t)bi * NPH * NPW * 64;
    const int ph0 = (ci > 0) ? ci - 1 : 0;     // clamped patch rows
    const int ph1 = (ci < NPH) ? ci : NPH - 1;
    const bool vh0 = (ci > 0), vh1 = (ci < NPH);

    #pragma unroll
    for (int half = 0; half < 2; ++half) {
      uint2 zv[4][4];
      int   cja[4];
      // batch-issue 16 loads (no branches between them)
      #pragma unroll
      for (int i = 0; i < 4; ++i) {
        const int c  = (half * 4 + i) * 4 + r; // cell 0..31 (wave-uniform)
        const int cj = seg * 32 + c;
        cja[i] = cj;
        const int pw0 = (cj > 0) ? cj - 1 : 0;
        const int pw1 = (cj < NPW) ? cj : NPW - 1;
        zv[i][0] = zb[((size_t)ph0 * NPW + pw0) * 64 + l];
        zv[i][1] = zb[((size_t)ph0 * NPW + pw1) * 64 + l];
        zv[i][2] = zb[((size_t)ph1 * NPW + pw0) * 64 + l];
        zv[i][3] = zb[((size_t)ph1 * NPW + pw1) * 64 + l];
      }
      // accumulate with validity masks (wave-uniform), store to LDS
      #pragma unroll
      for (int i = 0; i < 4; ++i) {
        const int c  = (half * 4 + i) * 4 + r;
        const int cj = cja[i];
        const bool vw0 = (cj > 0), vw1 = (cj < NPW);
        float a0 = 0.f, a1 = 0.f, a2 = 0.f, a3 = 0.f;
        #pragma unroll
        for (int k = 0; k < 4; ++k) {
          const bool ok = (k < 2 ? vh0 : vh1) && ((k & 1) == 0 ? vw0 : vw1);
          uint2 z = zv[i][k];
          if (!ok) { z.x = 0u; z.y = 0u; }     // uniform, post-load
          a0 += blo2f(z.x); a1 += bhi2f(z.x);
          a2 += blo2f(z.y); a3 += bhi2f(z.y);
        }
        const float cntw = 2.0f - (cj == 0) - (cj == NCELL - 1);
        const float s = 1.0f / (cnth * cntw);
        const int base = c * 128;
        const int u0 = 8 * u + (j >> 2);       // d2x>>2 (pair 2u)
        const int u1 = u0 + 4;                 // d2y>>2 (pair 2u+1)
        Wl[base + (((u0 + c) & 31) << 2) + (j & 3)] = pack2bf(s * a0, s * a1);
        Wl[base + (((u1 + c) & 31) << 2) + (j & 3)] = pack2bf(s * a2, s * a3);
      }
    }
  }
  __syncthreads();

  // ---- phase B: out = x - W*x  (thread: one float2, all 16 channels)
  const int cl = q2 >> 1;                      // lane's cell 0..31
  float* po = ob + (size_t)h * WDIM + wpx;
  #pragma unroll
  for (int cp = 0; cp < 8; ++cp) {
    float2 d0 = {0.f, 0.f};
    float2 d1 = {0.f, 0.f};
    #pragma unroll
    for (int k = 0; k < 4; ++k) {
      const uint4 V = *(const uint4*)&Wl[cl * 128 + (((4 * cp + k + cl) & 31) << 2)];
      const unsigned int va[4] = {V.x, V.y, V.z, V.w};
      #pragma unroll
      for (int c = 0; c < 4; ++c) {
        const int e = 4 * k + c;
        const float wlo = blo2f(va[c]);        // out-ch 2cp,   in-ch e
        const float whi = bhi2f(va[c]);        // out-ch 2cp+1, in-ch e
        d0.x += wlo * xv[e].x; d0.y += wlo * xv[e].y;
        d1.x += whi * xv[e].x; d1.y += whi * xv[e].y;
      }
    }
    const int c0 = 2 * cp, c1 = 2 * cp + 1;
    float2 o0, o1;
    o0.x = xv[c0].x - d0.x; o0.y = xv[c0].y - d0.y;
    o1.x = xv[c1].x - d1.x; o1.y = xv[c1].y - d1.y;
    *(float2*)(po + (size_t)c0 * HW) = o0;
    *(float2*)(po + (size_t)c1 * HW) = o1;
  }
}

extern "C" void kernel_launch(void* const* d_in, const int* in_sizes, int n_in,
                              void* d_out, int out_size, void* d_ws, size_t ws_size,
                              hipStream_t stream) {
  const float* x = (const float*)d_in[0];
  float* out = (float*)d_out;
  uint2* zs = (uint2*)d_ws;                    // 32258*512B = 16.5 MB

  llr_zs<<<dim3(ZS_NBLK), dim3(256), 0, stream>>>(x, zs);
  llr_strip<<<dim3(ST_NBLK), dim3(256), 0, stream>>>(x, zs, out);
}